// Round 1
// baseline (1858.802 us; speedup 1.0000x reference)
//
#include <hip/hip_runtime.h>
#include <stdint.h>
#include <string.h>

#define XH   256      // x_size == h_size
#define NCLS 104
#define TM   128      // node rows per k_conv block
#define BK   32       // K-chunk width
#define LSTRIDE 33    // padded fp32 LDS accumulator stride (bank-conflict break)

typedef __attribute__((ext_vector_type(8))) short  short8;
typedef __attribute__((ext_vector_type(4))) float  floatx4;
typedef __attribute__((ext_vector_type(4))) int    intx4;

__device__ __forceinline__ float bf2f(unsigned short u) {
    unsigned v = ((unsigned)u) << 16;
    return __builtin_bit_cast(float, v);
}
__device__ __forceinline__ unsigned short f2bf(float f) {
    unsigned v = __builtin_bit_cast(unsigned, f);
    unsigned r = (v + 0x7fffu + ((v >> 16) & 1u)) >> 16;
    return (unsigned short)r;
}

__device__ __forceinline__ int lower_bound(const int* a, int n, int v) {
    int lo = 0, hi = n;
    while (lo < hi) { int m = (lo + hi) >> 1; if (a[m] < v) lo = m + 1; else hi = m; }
    return lo;
}

// ---------------------------------------------------------------------------
// Bt[m][c][k] = W_m[k][c] as bf16  (m: 0=W_left, 1=W_right, 2=W_top)
// Transposed so MFMA B-fragments (lane n holds 8 consecutive k) are contiguous.
// ---------------------------------------------------------------------------
__global__ void k_prep_B(const float* __restrict__ Wl, const float* __restrict__ Wr,
                         const float* __restrict__ Wt, unsigned short* __restrict__ Bt) {
    int o = blockIdx.x * blockDim.x + threadIdx.x;
    if (o >= 3 * XH * XH) return;
    int m = o >> 16;
    int r = o & 65535;
    int c = r >> 8;
    int k = r & 255;
    const float* W = (m == 0) ? Wl : (m == 1) ? Wr : Wt;
    Bt[o] = f2bf(W[k * XH + c]);
}

// ---------------------------------------------------------------------------
// Fused: emb gather + edge segment-sums (left/right) + 3-way GEMM (K=768)
// + bias + relu + where(cc>0, conv, emb)  ->  h_out (bf16 [N,256])
// ---------------------------------------------------------------------------
__global__ __launch_bounds__(512)
void k_conv(const int* __restrict__ node_type, const int* __restrict__ edge_src,
            const int* __restrict__ edge_dst, const float* __restrict__ alpha,
            const int* __restrict__ child_count, const float* __restrict__ emb,
            const float* __restrict__ b_conv, const unsigned short* __restrict__ Bt,
            unsigned short* __restrict__ h_out, int N, int E) {
    const int t0  = blockIdx.x * TM;
    const int tid = threadIdx.x;

    __shared__ float accbuf[2 * TM * LSTRIDE];             // L then R fp32 accum (33.8 KB)
    __shared__ __align__(16) unsigned short Ab[TM * BK];   // bf16 A chunk (8 KB)
    __shared__ __align__(16) unsigned short Bb[XH * BK];   // bf16 B chunk, [c][k] (16 KB)

    // contiguous edge range of this node tile (edge_dst globally sorted)
    const int estart = lower_bound(edge_dst, E, t0);
    const int eend   = lower_bound(edge_dst, E, t0 + TM);

    const int lane = tid & 63;
    const int wv   = tid >> 6;   // 0..7
    const int mw   = wv >> 2;    // 0..1  (row 64-strip)
    const int nw   = wv & 3;     // 0..3  (col 64-strip)
    const int quad = lane >> 4;  // 0..3
    const int l15  = lane & 15;

    floatx4 acc[4][4];
    #pragma unroll
    for (int i = 0; i < 4; i++)
        #pragma unroll
        for (int j = 0; j < 4; j++)
            acc[i][j] = floatx4{0.f, 0.f, 0.f, 0.f};

    auto zero_acc = [&]() {
        for (int i = tid; i < 2 * TM * LSTRIDE; i += 512) accbuf[i] = 0.f;
    };

    auto edge_pass = [&](int kp) {
        const int j  = tid & 31;
        const int eg = tid >> 5;                // 16 edges in flight
        for (int e = estart + eg; e < eend; e += 16) {
            int   v = edge_dst[e] - t0;
            int   s = edge_src[e];
            float a = alpha[e];
            float x = emb[node_type[s] * XH + kp * BK + j];
            atomicAdd(&accbuf[v * LSTRIDE + j], (1.f - a) * x);
            atomicAdd(&accbuf[TM * LSTRIDE + v * LSTRIDE + j], a * x);
        }
    };

    auto cvt_A = [&](const float* accsrc) {     // fp32 accum -> bf16 A chunk
        int v = tid >> 2, k0 = (tid & 3) * 8;
        const float* p = &accsrc[v * LSTRIDE + k0];
        short8 s;
        #pragma unroll
        for (int i = 0; i < 8; i++) s[i] = (short)f2bf(p[i]);
        *(short8*)&Ab[v * BK + k0] = s;
    };

    auto gather_H = [&](int kp) {               // emb row slices -> bf16 A chunk
        int v = tid >> 2, k0 = (tid & 3) * 8;
        int tn = node_type[t0 + v];
        const float* p = &emb[tn * XH + kp * BK + k0];
        short8 s;
        #pragma unroll
        for (int i = 0; i < 8; i++) s[i] = (short)f2bf(p[i]);
        *(short8*)&Ab[v * BK + k0] = s;
    };

    auto stage_B = [&](int m, int kp) {         // 16 KB chunk, 16B granules
        const intx4* src = (const intx4*)Bt;
        for (int gr = tid; gr < (XH * BK) / 8; gr += 512) {
            int c = gr >> 2, kg = gr & 3;
            ((intx4*)Bb)[gr] = src[(m * XH * XH + c * XH + kp * BK) / 8 + kg];
        }
    };

    auto do_mfma = [&]() {
        short8 a[4];
        #pragma unroll
        for (int mt = 0; mt < 4; mt++) {
            int v = mw * 64 + mt * 16 + l15;
            a[mt] = *(const short8*)&Ab[v * BK + quad * 8];
        }
        #pragma unroll
        for (int nt = 0; nt < 4; nt++) {
            int c = nw * 64 + nt * 16 + l15;
            short8 b = *(const short8*)&Bb[c * BK + quad * 8];
            #pragma unroll
            for (int mt = 0; mt < 4; mt++)
                acc[mt][nt] = __builtin_amdgcn_mfma_f32_16x16x32_bf16(a[mt], b, acc[mt][nt], 0, 0, 0);
        }
    };

    // ---- left/right phases: one gather pass per 32-wide emb slice feeds both
    for (int kp = 0; kp < XH / BK; kp++) {
        zero_acc();
        __syncthreads();
        edge_pass(kp);
        __syncthreads();
        cvt_A(&accbuf[0]);                // left
        stage_B(0, kp);
        __syncthreads();
        do_mfma();
        __syncthreads();
        cvt_A(&accbuf[TM * LSTRIDE]);     // right
        stage_B(1, kp);
        __syncthreads();
        do_mfma();
        __syncthreads();
    }
    // ---- h @ W_top phase
    for (int kp = 0; kp < XH / BK; kp++) {
        gather_H(kp);
        stage_B(2, kp);
        __syncthreads();
        do_mfma();
        __syncthreads();
    }

    // ---- epilogue: bias + relu + where(cc>0, conv, emb) -> bf16
    #pragma unroll
    for (int nt = 0; nt < 4; nt++) {
        int col = nw * 64 + nt * 16 + l15;
        float bias = b_conv[col];
        #pragma unroll
        for (int mt = 0; mt < 4; mt++) {
            #pragma unroll
            for (int r = 0; r < 4; r++) {
                int row = t0 + mw * 64 + mt * 16 + quad * 4 + r;
                float x = acc[mt][nt][r] + bias;
                x = fmaxf(x, 0.f);
                if (child_count[row] == 0)
                    x = emb[node_type[row] * XH + col];
                h_out[row * XH + col] = f2bf(x);
            }
        }
    }
}

// ---------------------------------------------------------------------------
// Per-graph: gate = h@gate_w + gate_b; softmax (shift-free: |gate| << 1);
// pooled = sum(attn*h); out = pooled@cls_w + cls_b.  One block per graph.
// ---------------------------------------------------------------------------
__global__ __launch_bounds__(256)
void k_pool(const unsigned short* __restrict__ h_out,
            const float* __restrict__ gate_w, const float* __restrict__ gate_b,
            const float* __restrict__ cls_w, const float* __restrict__ cls_b,
            float* __restrict__ out, int PER) {
    const int g    = blockIdx.x;
    const int tid  = threadIdx.x;
    const int lane = tid & 63;
    const int wv   = tid >> 6;      // 4 waves

    __shared__ float e_lds[1024];
    __shared__ float pooled[XH];
    __shared__ float denom;
    if (tid == 0) denom = 0.f;
    __syncthreads();

    const int base = g * PER;
    const float gb = gate_b[0];

    float gw[4];
    #pragma unroll
    for (int i = 0; i < 4; i++) gw[i] = gate_w[lane * 4 + i];

    // phase A: gate score + exp per node (one wave per node, 64x4 features)
    float dsum = 0.f;
    for (int v = wv; v < PER; v += 4) {
        const unsigned short* hp = &h_out[(base + v) * XH + lane * 4];
        float s = 0.f;
        #pragma unroll
        for (int i = 0; i < 4; i++) s += bf2f(hp[i]) * gw[i];
        #pragma unroll
        for (int off = 32; off > 0; off >>= 1) s += __shfl_down(s, off);
        if (lane == 0) {
            float e = expf(s + gb);
            e_lds[v] = e;
            dsum += e;
        }
    }
    if (lane == 0) atomicAdd(&denom, dsum);
    __syncthreads();

    // phase B: pooled[k] = sum_v e[v]*h[v,k]  (thread k owns a column)
    float accp = 0.f;
    const unsigned short* hb = &h_out[base * XH];
    #pragma unroll 8
    for (int v = 0; v < PER; v++)
        accp += e_lds[v] * bf2f(hb[v * XH + tid]);
    pooled[tid] = accp / denom;
    __syncthreads();

    // phase C: classifier
    if (tid < NCLS) {
        float o = cls_b[tid];
        #pragma unroll 8
        for (int k = 0; k < XH; k++) o += pooled[k] * cls_w[k * NCLS + tid];
        out[g * NCLS + tid] = o;
    }
}

// ---------------------------------------------------------------------------
extern "C" void kernel_launch(void* const* d_in, const int* in_sizes, int n_in,
                              void* d_out, int out_size, void* d_ws, size_t ws_size,
                              hipStream_t stream) {
    const int*   node_type   = (const int*)d_in[0];
    const int*   edge_src    = (const int*)d_in[1];
    const int*   edge_dst    = (const int*)d_in[2];
    const float* alpha       = (const float*)d_in[3];
    const int*   child_count = (const int*)d_in[4];
    // d_in[5] graph_ids unused: nodes of a graph are contiguous (N = G*PER)
    const float* emb         = (const float*)d_in[6];
    const float* Wl          = (const float*)d_in[7];
    const float* Wr          = (const float*)d_in[8];
    const float* Wt          = (const float*)d_in[9];
    const float* b_conv      = (const float*)d_in[10];
    const float* gate_w      = (const float*)d_in[11];
    const float* gate_b      = (const float*)d_in[12];
    const float* cls_w       = (const float*)d_in[13];
    const float* cls_b       = (const float*)d_in[14];

    const int N   = in_sizes[0];
    const int E   = in_sizes[1];
    const int G   = out_size / NCLS;
    const int PER = N / G;

    unsigned short* h_out = (unsigned short*)d_ws;                       // N*256 bf16
    unsigned short* Bt    = h_out + (size_t)N * XH;                      // 3*256*256 bf16

    hipLaunchKernelGGL(k_prep_B, dim3((3 * XH * XH + 255) / 256), dim3(256), 0, stream,
                       Wl, Wr, Wt, Bt);
    hipLaunchKernelGGL(k_conv, dim3(N / TM), dim3(512), 0, stream,
                       node_type, edge_src, edge_dst, alpha, child_count,
                       emb, b_conv, Bt, h_out, N, E);
    hipLaunchKernelGGL(k_pool, dim3(G), dim3(256), 0, stream,
                       h_out, gate_w, gate_b, cls_w, cls_b, (float*)d_out, PER);
}

// Round 2
// 367.945 us; speedup vs baseline: 5.0518x; 5.0518x over previous
//
#include <hip/hip_runtime.h>
#include <stdint.h>

#define XH   256      // x_size == h_size
#define NCLS 104
#define YW   768      // Y row width: [Yl(256) | Yr(256) | Yt(256)]
#define AST  40       // padded bf16 LDS tile stride (breaks 8-way bank conflict)

typedef __attribute__((ext_vector_type(8))) short          short8;
typedef __attribute__((ext_vector_type(4))) float          floatx4;
typedef __attribute__((ext_vector_type(4))) int            intx4;
typedef __attribute__((ext_vector_type(4))) unsigned short ushort4b;

__device__ __forceinline__ float bf2f(unsigned short u) {
    unsigned v = ((unsigned)u) << 16;
    return __builtin_bit_cast(float, v);
}
__device__ __forceinline__ unsigned short f2bf(float f) {
    unsigned v = __builtin_bit_cast(unsigned, f);
    unsigned r = (v + 0x7fffu + ((v >> 16) & 1u)) >> 16;
    return (unsigned short)r;
}
__device__ __forceinline__ int lower_bound(const int* __restrict__ a, int n, int v) {
    int lo = 0, hi = n;
    while (lo < hi) { int m = (lo + hi) >> 1; if (a[m] < v) lo = m + 1; else hi = m; }
    return lo;
}

// ---------------------------------------------------------------------------
// Btw[m*256+c][k] = W_m[k][c] as bf16 (m: 0=Wl, 1=Wr, 2=Wt) -> B is k-contiguous
// ---------------------------------------------------------------------------
__global__ void k_prep(const float* __restrict__ Wl, const float* __restrict__ Wr,
                       const float* __restrict__ Wt, unsigned short* __restrict__ Btw) {
    int o = blockIdx.x * blockDim.x + threadIdx.x;
    if (o >= 3 * XH * XH) return;
    int m = o >> 16;
    int r = o & 65535;
    int c = r >> 8;     // output column within W_m
    int k = r & 255;    // reduction index
    const float* W = (m == 0) ? Wl : (m == 1) ? Wr : Wt;
    Btw[o] = f2bf(W[k * XH + c]);
}

// ---------------------------------------------------------------------------
// Y[vocab][768] bf16 = emb[vocab][256] @ [Wl | Wr | Wt]   (12.9 GFLOP)
// tile 128x128, K=256 in 8 chunks of 32, 4 waves in 2x2, 16x16x32 bf16 MFMA
// ---------------------------------------------------------------------------
__global__ __launch_bounds__(256)
void k_gemm(const float* __restrict__ emb, const unsigned short* __restrict__ Btw,
            unsigned short* __restrict__ Y, int vocab) {
    const int m0 = blockIdx.x * 128;
    const int n0 = blockIdx.y * 128;
    const int tid = threadIdx.x;
    const int lane = tid & 63;
    const int wv   = tid >> 6;
    const int mw   = wv >> 1;    // 0..1
    const int nw   = wv & 1;     // 0..1
    const int quad = lane >> 4;
    const int l15  = lane & 15;

    __shared__ __align__(16) unsigned short Ab[128 * AST];
    __shared__ __align__(16) unsigned short Bb[128 * AST];

    floatx4 acc[4][4];
    #pragma unroll
    for (int i = 0; i < 4; i++)
        #pragma unroll
        for (int j = 0; j < 4; j++) acc[i][j] = floatx4{0.f, 0.f, 0.f, 0.f};

    const int sr = tid >> 1;          // staging row/col 0..127
    const int kh = (tid & 1) * 16;    // k half

    for (int kc = 0; kc < 8; kc++) {
        // stage A: emb fp32 -> bf16
        {
            int row = min(m0 + sr, vocab - 1);
            const float* ga = &emb[(size_t)row * XH + kc * 32 + kh];
            short8 s0, s1;
            #pragma unroll
            for (int i = 0; i < 8; i++) s0[i] = (short)f2bf(ga[i]);
            #pragma unroll
            for (int i = 0; i < 8; i++) s1[i] = (short)f2bf(ga[8 + i]);
            *(short8*)&Ab[sr * AST + kh]     = s0;
            *(short8*)&Ab[sr * AST + kh + 8] = s1;
        }
        // stage B: Btw bf16 direct
        {
            const unsigned short* gb = &Btw[(size_t)(n0 + sr) * XH + kc * 32 + kh];
            *(intx4*)&Bb[sr * AST + kh]     = *(const intx4*)&gb[0];
            *(intx4*)&Bb[sr * AST + kh + 8] = *(const intx4*)&gb[8];
        }
        __syncthreads();
        short8 a[4];
        #pragma unroll
        for (int mt = 0; mt < 4; mt++)
            a[mt] = *(const short8*)&Ab[(mw * 64 + mt * 16 + l15) * AST + quad * 8];
        #pragma unroll
        for (int nt = 0; nt < 4; nt++) {
            short8 b = *(const short8*)&Bb[(nw * 64 + nt * 16 + l15) * AST + quad * 8];
            #pragma unroll
            for (int mt = 0; mt < 4; mt++)
                acc[mt][nt] = __builtin_amdgcn_mfma_f32_16x16x32_bf16(a[mt], b, acc[mt][nt], 0, 0, 0);
        }
        __syncthreads();
    }

    #pragma unroll
    for (int nt = 0; nt < 4; nt++) {
        int col = n0 + nw * 64 + nt * 16 + l15;
        #pragma unroll
        for (int mt = 0; mt < 4; mt++) {
            #pragma unroll
            for (int r = 0; r < 4; r++) {
                int row = m0 + mw * 64 + mt * 16 + quad * 4 + r;
                if (row < vocab) Y[(size_t)row * YW + col] = f2bf(acc[mt][nt][r]);
            }
        }
    }
}

// ---------------------------------------------------------------------------
// One block per graph, 16 waves, one node per wave-iteration.
// h row lives in registers (4 floats/lane); fused gate -> exp -> pool -> cls.
// ---------------------------------------------------------------------------
__global__ __launch_bounds__(1024)
void k_graph(const int* __restrict__ node_type, const int* __restrict__ edge_src,
             const int* __restrict__ edge_dst, const float* __restrict__ alpha,
             const int* __restrict__ child_count, const float* __restrict__ emb,
             const float* __restrict__ b_conv, const float* __restrict__ gate_w,
             const float* __restrict__ gate_b, const float* __restrict__ cls_w,
             const float* __restrict__ cls_b, const unsigned short* __restrict__ Y,
             float* __restrict__ out, int PER, int E) {
    const int g    = blockIdx.x;
    const int tid  = threadIdx.x;
    const int lane = tid & 63;
    const int wv   = tid >> 6;       // 16 waves
    const int NW   = 16;

    __shared__ float poolw[NW * XH];
    __shared__ float dsums[NW];
    __shared__ float pooled[XH];

    float gw4[4], bc4[4];
    #pragma unroll
    for (int i = 0; i < 4; i++) gw4[i] = gate_w[4 * lane + i];
    #pragma unroll
    for (int i = 0; i < 4; i++) bc4[i] = b_conv[4 * lane + i];
    const float gb = gate_b[0];

    const int chunk = (PER + NW - 1) / NW;
    const int v0 = g * PER + wv * chunk;
    const int v1 = min(g * PER + PER, v0 + chunk);

    int ecur = lower_bound(edge_dst, E, v0);

    float acc4[4] = {0.f, 0.f, 0.f, 0.f};
    float dsum = 0.f;

    for (int v = v0; v < v1; v++) {
        int c = child_count[v];
        float h4[4];
        if (c == 0) {
            int tv = node_type[v];
            floatx4 hv = *(const floatx4*)&emb[(size_t)tv * XH + 4 * lane];
            #pragma unroll
            for (int i = 0; i < 4; i++) h4[i] = hv[i];
        } else {
            float s4[4] = {0.f, 0.f, 0.f, 0.f};
            for (int e = ecur; e < ecur + c; e++) {
                int   s  = edge_src[e];
                float a  = alpha[e];
                int   ts = node_type[s];
                ushort4b yl = *(const ushort4b*)&Y[(size_t)ts * YW + 4 * lane];
                ushort4b yr = *(const ushort4b*)&Y[(size_t)ts * YW + XH + 4 * lane];
                float w0 = 1.f - a;
                #pragma unroll
                for (int i = 0; i < 4; i++)
                    s4[i] += w0 * bf2f(yl[i]) + a * bf2f(yr[i]);
            }
            ecur += c;
            int tv = node_type[v];
            ushort4b yt = *(const ushort4b*)&Y[(size_t)tv * YW + 2 * XH + 4 * lane];
            #pragma unroll
            for (int i = 0; i < 4; i++)
                h4[i] = fmaxf(s4[i] + bf2f(yt[i]) + bc4[i], 0.f);
        }
        // gate score across the 256-wide row
        float sg = h4[0] * gw4[0] + h4[1] * gw4[1] + h4[2] * gw4[2] + h4[3] * gw4[3];
        #pragma unroll
        for (int o = 1; o < 64; o <<= 1) sg += __shfl_xor(sg, o);
        float e = __expf(sg + gb);
        dsum += e;
        #pragma unroll
        for (int i = 0; i < 4; i++) acc4[i] += e * h4[i];
    }

    #pragma unroll
    for (int i = 0; i < 4; i++) poolw[wv * XH + 4 * lane + i] = acc4[i];
    if (lane == 0) dsums[wv] = dsum;
    __syncthreads();

    if (tid < XH) {
        float p = 0.f, d = 0.f;
        #pragma unroll
        for (int w = 0; w < NW; w++) p += poolw[w * XH + tid];
        #pragma unroll
        for (int w = 0; w < NW; w++) d += dsums[w];
        pooled[tid] = p / d;
    }
    __syncthreads();

    if (tid < NCLS) {
        float o = cls_b[tid];
        #pragma unroll 8
        for (int k = 0; k < XH; k++) o += pooled[k] * cls_w[k * NCLS + tid];
        out[g * NCLS + tid] = o;
    }
}

// ---------------------------------------------------------------------------
extern "C" void kernel_launch(void* const* d_in, const int* in_sizes, int n_in,
                              void* d_out, int out_size, void* d_ws, size_t ws_size,
                              hipStream_t stream) {
    const int*   node_type   = (const int*)d_in[0];
    const int*   edge_src    = (const int*)d_in[1];
    const int*   edge_dst    = (const int*)d_in[2];
    const float* alpha       = (const float*)d_in[3];
    const int*   child_count = (const int*)d_in[4];
    // d_in[5] graph_ids unused: nodes of a graph are contiguous
    const float* emb         = (const float*)d_in[6];
    const float* Wl          = (const float*)d_in[7];
    const float* Wr          = (const float*)d_in[8];
    const float* Wt          = (const float*)d_in[9];
    const float* b_conv      = (const float*)d_in[10];
    const float* gate_w      = (const float*)d_in[11];
    const float* gate_b      = (const float*)d_in[12];
    const float* cls_w       = (const float*)d_in[13];
    const float* cls_b       = (const float*)d_in[14];

    const int N     = in_sizes[0];
    const int E     = in_sizes[1];
    const int vocab = in_sizes[6] / XH;
    const int G     = out_size / NCLS;
    const int PER   = N / G;

    unsigned short* Y   = (unsigned short*)d_ws;                 // vocab*768 bf16
    unsigned short* Btw = Y + (size_t)vocab * YW;                // 3*256*256 bf16

    hipLaunchKernelGGL(k_prep, dim3((3 * XH * XH + 255) / 256), dim3(256), 0, stream,
                       Wl, Wr, Wt, Btw);
    hipLaunchKernelGGL(k_gemm, dim3((vocab + 127) / 128, YW / 128), dim3(256), 0, stream,
                       emb, Btw, Y, vocab);
    hipLaunchKernelGGL(k_graph, dim3(G), dim3(1024), 0, stream,
                       node_type, edge_src, edge_dst, alpha, child_count, emb,
                       b_conv, gate_w, gate_b, cls_w, cls_b, Y, (float*)d_out, PER, E);
}

// Round 3
// 255.067 us; speedup vs baseline: 7.2875x; 1.4425x over previous
//
#include <hip/hip_runtime.h>
#include <stdint.h>

#define XH   256      // x_size == h_size
#define NCLS 104
#define YW   768      // Y row: [Yl(256) | Yr(256) | Yt(256)]

typedef __attribute__((ext_vector_type(8))) short          short8;
typedef __attribute__((ext_vector_type(4))) float          floatx4;
typedef __attribute__((ext_vector_type(4))) unsigned short ushort4b;

__device__ __forceinline__ float bf2f(unsigned short u) {
    unsigned v = ((unsigned)u) << 16;
    return __builtin_bit_cast(float, v);
}
__device__ __forceinline__ unsigned short f2bf(float f) {
    unsigned v = __builtin_bit_cast(unsigned, f);
    unsigned r = (v + 0x7fffu + ((v >> 16) & 1u)) >> 16;
    return (unsigned short)r;
}
__device__ __forceinline__ void gll16(const void* g, void* l) {
    __builtin_amdgcn_global_load_lds(
        (const __attribute__((address_space(1))) unsigned*)g,
        (__attribute__((address_space(3))) unsigned*)l, 16, 0, 0);
}

// ---------------------------------------------------------------------------
__global__ __launch_bounds__(256)
void k_zero(int* __restrict__ p, int n) {
    int i = blockIdx.x * 256 + threadIdx.x;
    if (i < n) p[i] = 0;
}

// ---------------------------------------------------------------------------
// A: emb fp32 -> embh bf16 (float4 granules)
// B: Btw[m*256+c][k] = W_m[k][c] bf16
// C: epk[e] = { node_type[edge_src[e]]*768, alpha[e] }; row_start CSR scatter
// ---------------------------------------------------------------------------
__global__ __launch_bounds__(256)
void k_prep_all(const float* __restrict__ emb, const float* __restrict__ Wl,
                const float* __restrict__ Wr, const float* __restrict__ Wt,
                const int* __restrict__ edge_src, const int* __restrict__ edge_dst,
                const float* __restrict__ alpha, const int* __restrict__ node_type,
                unsigned short* __restrict__ embh, unsigned short* __restrict__ Btw,
                int2* __restrict__ epk, int* __restrict__ row_start,
                int vocab, int E) {
    int idx = blockIdx.x * 256 + threadIdx.x;
    int nA = vocab * (XH / 4);
    if (idx < nA) {
        floatx4 f = *(const floatx4*)&emb[(size_t)idx * 4];
        ushort4b u;
        #pragma unroll
        for (int i = 0; i < 4; i++) u[i] = f2bf(f[i]);
        *(ushort4b*)&embh[(size_t)idx * 4] = u;
        return;
    }
    idx -= nA;
    int nB = 3 * XH * XH;
    if (idx < nB) {
        int m = idx >> 16, r = idx & 65535, c = r >> 8, k = r & 255;
        const float* W = (m == 0) ? Wl : (m == 1) ? Wr : Wt;
        Btw[idx] = f2bf(W[k * XH + c]);
        return;
    }
    idx -= nB;
    if (idx < E) {
        int s = edge_src[idx];
        int2 p;
        p.x = node_type[s] * YW;
        p.y = __float_as_int(alpha[idx]);
        epk[idx] = p;
        int d = edge_dst[idx];
        if (idx == 0 || edge_dst[idx - 1] != d) row_start[d] = idx;
    }
}

// ---------------------------------------------------------------------------
// Y[vocab][768] bf16 = embh @ [Wl|Wr|Wt]; m97-style global_load_lds staging.
// tile 128x128, BK=32 (8 chunks), 4 waves 2x2, 16x16x32 bf16 MFMA
// ---------------------------------------------------------------------------
__global__ __launch_bounds__(256)
void k_gemm(const unsigned short* __restrict__ embh,
            const unsigned short* __restrict__ Btw,
            unsigned short* __restrict__ Y) {
    const int m0 = blockIdx.x * 128;
    const int n0 = blockIdx.y * 128;
    const int tid  = threadIdx.x;
    const int lane = tid & 63;
    const int wv   = tid >> 6;
    const int mw   = wv >> 1;
    const int nw   = wv & 1;
    const int quad = lane >> 4;
    const int l15  = lane & 15;

    __shared__ __align__(16) unsigned short Ab[128 * 32];  // 8 KB, rows of 64 B
    __shared__ __align__(16) unsigned short Bb[128 * 32];

    floatx4 acc[4][4];
    #pragma unroll
    for (int i = 0; i < 4; i++)
        #pragma unroll
        for (int j = 0; j < 4; j++) acc[i][j] = floatx4{0.f, 0.f, 0.f, 0.f};

    const int lq = lane >> 2;        // row within a 16-row staging group
    const int lb = (lane & 3) * 16;  // byte column within 64 B row

    for (int kc = 0; kc < 8; kc++) {
        #pragma unroll
        for (int i = 0; i < 2; i++) {
            int issue = wv * 2 + i;
            int row   = issue * 16 + lq;
            gll16((const char*)embh + (size_t)(m0 + row) * 512 + kc * 64 + lb,
                  (char*)Ab + issue * 1024);
            gll16((const char*)Btw + (size_t)(n0 + row) * 512 + kc * 64 + lb,
                  (char*)Bb + issue * 1024);
        }
        __syncthreads();
        short8 a[4];
        #pragma unroll
        for (int mt = 0; mt < 4; mt++)
            a[mt] = *(const short8*)((const char*)Ab + (mw * 64 + mt * 16 + l15) * 64 + quad * 16);
        #pragma unroll
        for (int nt = 0; nt < 4; nt++) {
            short8 b = *(const short8*)((const char*)Bb + (nw * 64 + nt * 16 + l15) * 64 + quad * 16);
            #pragma unroll
            for (int mt = 0; mt < 4; mt++)
                acc[mt][nt] = __builtin_amdgcn_mfma_f32_16x16x32_bf16(a[mt], b, acc[mt][nt], 0, 0, 0);
        }
        __syncthreads();
    }

    #pragma unroll
    for (int nt = 0; nt < 4; nt++) {
        int col = n0 + nw * 64 + nt * 16 + l15;
        #pragma unroll
        for (int mt = 0; mt < 4; mt++) {
            #pragma unroll
            for (int r = 0; r < 4; r++) {
                int row = m0 + mw * 64 + mt * 16 + quad * 4 + r;
                Y[(size_t)row * YW + col] = f2bf(acc[mt][nt][r]);
            }
        }
    }
}

// ---------------------------------------------------------------------------
// 2 blocks per graph x 8 waves = 16 wave-slots; slot s owns nodes s, s+16, ...
// Fused: h (registers) -> gate -> exp -> partial pool; atomics into pool_ws.
// ---------------------------------------------------------------------------
__global__ __launch_bounds__(512, 8)
void k_graph(const int* __restrict__ node_type, const int* __restrict__ child_count,
             const unsigned short* __restrict__ embh, const unsigned short* __restrict__ Y,
             const int2* __restrict__ epk, const int* __restrict__ row_start,
             const float* __restrict__ b_conv, const float* __restrict__ gate_w,
             const float* __restrict__ gate_b, float* __restrict__ pool_ws, int PER) {
    const int g    = blockIdx.x >> 1;
    const int half = blockIdx.x & 1;
    const int tid  = threadIdx.x;
    const int lane = tid & 63;
    const int wv   = tid >> 6;          // 0..7
    const int slot = half * 8 + wv;     // 0..15
    const int base = g * PER;

    __shared__ float pw[8 * XH];
    __shared__ float ds[8];

    float gw4[4], bc4[4];
    #pragma unroll
    for (int i = 0; i < 4; i++) gw4[i] = gate_w[4 * lane + i];
    #pragma unroll
    for (int i = 0; i < 4; i++) bc4[i] = b_conv[4 * lane + i];
    const float gb = gate_b[0];

    float acc4[4] = {0.f, 0.f, 0.f, 0.f};
    float dsum = 0.f;

    int vg = base + slot;
    int c  = child_count[vg];
    int tv = node_type[vg];
    int rs = row_start[vg];

    for (int v = slot; v < PER; v += 16) {
        // prefetch next node's metadata (hides ~200-cyc L2 latency)
        int cn = 0, tvn = 0, rsn = 0;
        if (v + 16 < PER) {
            cn  = child_count[vg + 16];
            tvn = node_type[vg + 16];
            rsn = row_start[vg + 16];
        }

        float h4[4];
        if (c == 0) {
            ushort4b hv = *(const ushort4b*)&embh[(size_t)tv * XH + 4 * lane];
            #pragma unroll
            for (int i = 0; i < 4; i++) h4[i] = bf2f(hv[i]);
        } else {
            ushort4b yt = *(const ushort4b*)&Y[(size_t)tv * YW + 2 * XH + 4 * lane];  // early
            float s4[4] = {0.f, 0.f, 0.f, 0.f};
            int e = rs, e1 = rs + c;
            for (; e + 2 <= e1; e += 2) {
                int2 p0 = epk[e], p1 = epk[e + 1];
                float a0 = __int_as_float(p0.y), a1 = __int_as_float(p1.y);
                // alpha==0/1: point both loads at the same row (same cache line)
                int oL0 = p0.x + (a0 == 1.f ? XH : 0);
                int oR0 = p0.x + (a0 == 0.f ? 0 : XH);
                int oL1 = p1.x + (a1 == 1.f ? XH : 0);
                int oR1 = p1.x + (a1 == 0.f ? 0 : XH);
                ushort4b yl0 = *(const ushort4b*)&Y[(size_t)oL0 + 4 * lane];
                ushort4b yr0 = *(const ushort4b*)&Y[(size_t)oR0 + 4 * lane];
                ushort4b yl1 = *(const ushort4b*)&Y[(size_t)oL1 + 4 * lane];
                ushort4b yr1 = *(const ushort4b*)&Y[(size_t)oR1 + 4 * lane];
                float w0 = 1.f - a0, w1 = 1.f - a1;
                #pragma unroll
                for (int i = 0; i < 4; i++)
                    s4[i] += w0 * bf2f(yl0[i]) + a0 * bf2f(yr0[i])
                           + w1 * bf2f(yl1[i]) + a1 * bf2f(yr1[i]);
            }
            if (e < e1) {
                int2 p0 = epk[e];
                float a0 = __int_as_float(p0.y);
                int oL0 = p0.x + (a0 == 1.f ? XH : 0);
                int oR0 = p0.x + (a0 == 0.f ? 0 : XH);
                ushort4b yl0 = *(const ushort4b*)&Y[(size_t)oL0 + 4 * lane];
                ushort4b yr0 = *(const ushort4b*)&Y[(size_t)oR0 + 4 * lane];
                float w0 = 1.f - a0;
                #pragma unroll
                for (int i = 0; i < 4; i++)
                    s4[i] += w0 * bf2f(yl0[i]) + a0 * bf2f(yr0[i]);
            }
            #pragma unroll
            for (int i = 0; i < 4; i++)
                h4[i] = fmaxf(s4[i] + bf2f(yt[i]) + bc4[i], 0.f);
        }

        float sg = h4[0] * gw4[0] + h4[1] * gw4[1] + h4[2] * gw4[2] + h4[3] * gw4[3];
        #pragma unroll
        for (int o = 1; o < 64; o <<= 1) sg += __shfl_xor(sg, o);
        float ew = __expf(sg + gb);
        dsum += ew;
        #pragma unroll
        for (int i = 0; i < 4; i++) acc4[i] += ew * h4[i];

        c = cn; tv = tvn; rs = rsn; vg += 16;
    }

    #pragma unroll
    for (int i = 0; i < 4; i++) pw[wv * XH + 4 * lane + i] = acc4[i];
    if (lane == 0) ds[wv] = dsum;
    __syncthreads();

    if (tid < XH) {
        float p = 0.f;
        #pragma unroll
        for (int w = 0; w < 8; w++) p += pw[w * XH + tid];
        atomicAdd(&pool_ws[g * (XH + 1) + tid], p);
    } else if (tid == XH) {
        float d = 0.f;
        #pragma unroll
        for (int w = 0; w < 8; w++) d += ds[w];
        atomicAdd(&pool_ws[g * (XH + 1) + XH], d);
    }
}

// ---------------------------------------------------------------------------
__global__ __launch_bounds__(256)
void k_final(const float* __restrict__ pool_ws, const float* __restrict__ cls_w,
             const float* __restrict__ cls_b, float* __restrict__ out) {
    const int g = blockIdx.x, tid = threadIdx.x;
    __shared__ float pooled[XH];
    float d = pool_ws[g * (XH + 1) + XH];
    pooled[tid] = pool_ws[g * (XH + 1) + tid] / d;
    __syncthreads();
    if (tid < NCLS) {
        float o = cls_b[tid];
        #pragma unroll 8
        for (int k = 0; k < XH; k++) o += pooled[k] * cls_w[k * NCLS + tid];
        out[g * NCLS + tid] = o;
    }
}

// ---------------------------------------------------------------------------
extern "C" void kernel_launch(void* const* d_in, const int* in_sizes, int n_in,
                              void* d_out, int out_size, void* d_ws, size_t ws_size,
                              hipStream_t stream) {
    const int*   node_type   = (const int*)d_in[0];
    const int*   edge_src    = (const int*)d_in[1];
    const int*   edge_dst    = (const int*)d_in[2];
    const float* alpha       = (const float*)d_in[3];
    const int*   child_count = (const int*)d_in[4];
    // d_in[5] graph_ids unused: nodes of a graph are contiguous
    const float* emb         = (const float*)d_in[6];
    const float* Wl          = (const float*)d_in[7];
    const float* Wr          = (const float*)d_in[8];
    const float* Wt          = (const float*)d_in[9];
    const float* b_conv      = (const float*)d_in[10];
    const float* gate_w      = (const float*)d_in[11];
    const float* gate_b      = (const float*)d_in[12];
    const float* cls_w       = (const float*)d_in[13];
    const float* cls_b       = (const float*)d_in[14];

    const int N     = in_sizes[0];
    const int E     = in_sizes[1];
    const int vocab = in_sizes[6] / XH;
    const int G     = out_size / NCLS;
    const int PER   = N / G;

    unsigned short* Y      = (unsigned short*)d_ws;            // vocab*768 bf16
    unsigned short* embh   = Y + (size_t)vocab * YW;           // vocab*256 bf16
    unsigned short* Btw    = embh + (size_t)vocab * XH;        // 3*256*256 bf16
    int2*           epk    = (int2*)(Btw + 3 * XH * XH);       // E * 8B
    int*            row_start = (int*)(epk + E);               // N * 4B
    float*          pool_ws   = (float*)(row_start + N);       // G*257 * 4B

    const int nzero = N + G * (XH + 1);
    hipLaunchKernelGGL(k_zero, dim3((nzero + 255) / 256), dim3(256), 0, stream,
                       row_start, nzero);

    const int nprep = vocab * (XH / 4) + 3 * XH * XH + E;
    hipLaunchKernelGGL(k_prep_all, dim3((nprep + 255) / 256), dim3(256), 0, stream,
                       emb, Wl, Wr, Wt, edge_src, edge_dst, alpha, node_type,
                       embh, Btw, epk, row_start, vocab, E);

    hipLaunchKernelGGL(k_gemm, dim3(vocab / 128, YW / 128), dim3(256), 0, stream,
                       embh, Btw, Y);

    hipLaunchKernelGGL(k_graph, dim3(2 * G), dim3(512), 0, stream,
                       node_type, child_count, embh, Y, epk, row_start,
                       b_conv, gate_w, gate_b, pool_ws, PER);

    hipLaunchKernelGGL(k_final, dim3(G), dim3(256), 0, stream,
                       pool_ws, cls_w, cls_b, (float*)d_out);
}

// Round 4
// 243.509 us; speedup vs baseline: 7.6334x; 1.0475x over previous
//
#include <hip/hip_runtime.h>
#include <stdint.h>

#define XH   256      // x_size == h_size
#define NCLS 104

typedef __attribute__((ext_vector_type(8))) short          short8;
typedef __attribute__((ext_vector_type(4))) float          floatx4;
typedef __attribute__((ext_vector_type(4))) unsigned short ushort4b;
typedef __attribute__((ext_vector_type(8))) unsigned short ushort8b;

__device__ __forceinline__ float bf2f(unsigned short u) {
    unsigned v = ((unsigned)u) << 16;
    return __builtin_bit_cast(float, v);
}
__device__ __forceinline__ unsigned short f2bf(float f) {
    unsigned v = __builtin_bit_cast(unsigned, f);
    unsigned r = (v + 0x7fffu + ((v >> 16) & 1u)) >> 16;
    return (unsigned short)r;
}
__device__ __forceinline__ void gll16(const void* g, void* l) {
    __builtin_amdgcn_global_load_lds(
        (const __attribute__((address_space(1))) unsigned*)g,
        (__attribute__((address_space(3))) unsigned*)l, 16, 0, 0);
}

// ---------------------------------------------------------------------------
// A: emb fp32 -> embh bf16
// B: Btw[n][k]: n<512 -> W_{n&1}[k][n>>1] (LR-interleaved), n>=512 -> Wt[k][n-512]
// C: epk[e] = { node_type[edge_src[e]]*512 (Ylr elem offset), alpha };
//    row_start CSR scatter (no zeroing needed: only read where child_count>0)
// ---------------------------------------------------------------------------
__global__ __launch_bounds__(256)
void k_prep(const float* __restrict__ emb, const float* __restrict__ Wl,
            const float* __restrict__ Wr, const float* __restrict__ Wt,
            const int* __restrict__ edge_src, const int* __restrict__ edge_dst,
            const float* __restrict__ alpha, const int* __restrict__ node_type,
            unsigned short* __restrict__ embh, unsigned short* __restrict__ Btw,
            int2* __restrict__ epk, int* __restrict__ row_start,
            int vocab, int E) {
    int idx = blockIdx.x * 256 + threadIdx.x;
    int nA = vocab * (XH / 4);
    if (idx < nA) {
        floatx4 f = *(const floatx4*)&emb[(size_t)idx * 4];
        ushort4b u;
        #pragma unroll
        for (int i = 0; i < 4; i++) u[i] = f2bf(f[i]);
        *(ushort4b*)&embh[(size_t)idx * 4] = u;
        return;
    }
    idx -= nA;
    int nB = 3 * XH * XH;
    if (idx < nB) {
        int n = idx >> 8, k = idx & 255;
        int m, c;
        if (n < 512) { m = n & 1; c = n >> 1; }
        else         { m = 2;     c = n - 512; }
        const float* W = (m == 0) ? Wl : (m == 1) ? Wr : Wt;
        Btw[idx] = f2bf(W[k * XH + c]);
        return;
    }
    idx -= nB;
    if (idx < E) {
        int s = edge_src[idx];
        int2 p;
        p.x = node_type[s] * 512;
        p.y = __float_as_int(alpha[idx]);
        epk[idx] = p;
        int d = edge_dst[idx];
        if (idx == 0 || edge_dst[idx - 1] != d) row_start[d] = idx;
    }
}

// ---------------------------------------------------------------------------
// [Ylr | Yt] = embh @ Btw^T; cols<512 -> Ylr (LR-interleaved), cols>=512 ->
// Yt with b_conv folded in. m97-style global_load_lds staging, tile 128x128.
// ---------------------------------------------------------------------------
__global__ __launch_bounds__(256)
void k_gemm(const unsigned short* __restrict__ embh,
            const unsigned short* __restrict__ Btw,
            const float* __restrict__ b_conv,
            unsigned short* __restrict__ Ylr, unsigned short* __restrict__ Yt) {
    const int m0 = blockIdx.x * 128;
    const int n0 = blockIdx.y * 128;
    const int tid  = threadIdx.x;
    const int lane = tid & 63;
    const int wv   = tid >> 6;
    const int mw   = wv >> 1;
    const int nw   = wv & 1;
    const int quad = lane >> 4;
    const int l15  = lane & 15;

    __shared__ __align__(16) unsigned short Ab[128 * 32];
    __shared__ __align__(16) unsigned short Bb[128 * 32];

    floatx4 acc[4][4];
    #pragma unroll
    for (int i = 0; i < 4; i++)
        #pragma unroll
        for (int j = 0; j < 4; j++) acc[i][j] = floatx4{0.f, 0.f, 0.f, 0.f};

    const int lq = lane >> 2;
    const int lb = (lane & 3) * 16;

    for (int kc = 0; kc < 8; kc++) {
        #pragma unroll
        for (int i = 0; i < 2; i++) {
            int issue = wv * 2 + i;
            int row   = issue * 16 + lq;
            gll16((const char*)embh + (size_t)(m0 + row) * 512 + kc * 64 + lb,
                  (char*)Ab + issue * 1024);
            gll16((const char*)Btw + (size_t)(n0 + row) * 512 + kc * 64 + lb,
                  (char*)Bb + issue * 1024);
        }
        __syncthreads();
        short8 a[4];
        #pragma unroll
        for (int mt = 0; mt < 4; mt++)
            a[mt] = *(const short8*)((const char*)Ab + (mw * 64 + mt * 16 + l15) * 64 + quad * 16);
        #pragma unroll
        for (int nt = 0; nt < 4; nt++) {
            short8 b = *(const short8*)((const char*)Bb + (nw * 64 + nt * 16 + l15) * 64 + quad * 16);
            #pragma unroll
            for (int mt = 0; mt < 4; mt++)
                acc[mt][nt] = __builtin_amdgcn_mfma_f32_16x16x32_bf16(a[mt], b, acc[mt][nt], 0, 0, 0);
        }
        __syncthreads();
    }

    const bool isT = (n0 >= 512);
    #pragma unroll
    for (int nt = 0; nt < 4; nt++) {
        int col = n0 + nw * 64 + nt * 16 + l15;
        float bias = isT ? b_conv[col - 512] : 0.f;
        #pragma unroll
        for (int mt = 0; mt < 4; mt++) {
            #pragma unroll
            for (int r = 0; r < 4; r++) {
                int row = m0 + mw * 64 + mt * 16 + quad * 4 + r;
                unsigned short val = f2bf(acc[mt][nt][r] + bias);
                if (isT) Yt[(size_t)row * XH + (col - 512)] = val;
                else     Ylr[(size_t)row * 512 + col] = val;
            }
        }
    }
}

// ---------------------------------------------------------------------------
// One 1024-thread block per graph; 16 wave-slots, slot s owns nodes s, s+16...
// Per edge: ONE 16B load (interleaved L/R pairs). Fully fused through the
// classifier — no workspace atomics, no final kernel.
// ---------------------------------------------------------------------------
__global__ __launch_bounds__(1024, 8)
void k_graph(const int* __restrict__ node_type, const int* __restrict__ child_count,
             const unsigned short* __restrict__ embh,
             const unsigned short* __restrict__ Ylr, const unsigned short* __restrict__ Yt,
             const int2* __restrict__ epk, const int* __restrict__ row_start,
             const float* __restrict__ gate_w, const float* __restrict__ gate_b,
             const float* __restrict__ cls_w, const float* __restrict__ cls_b,
             float* __restrict__ out, int PER) {
    const int g    = blockIdx.x;
    const int tid  = threadIdx.x;
    const int lane = tid & 63;
    const int wv   = tid >> 6;          // 0..15
    const int base = g * PER;

    __shared__ float pw[16 * XH];
    __shared__ float ds[16];
    __shared__ float pooled[XH];

    float gw4[4];
    #pragma unroll
    for (int i = 0; i < 4; i++) gw4[i] = gate_w[4 * lane + i];
    const float gb = gate_b[0];

    float acc4[4] = {0.f, 0.f, 0.f, 0.f};
    float dsum = 0.f;

    int vg = base + wv;
    int c  = child_count[vg];
    int tv = node_type[vg];
    int rs = row_start[vg];

    for (int v = wv; v < PER; v += 16) {
        int cn = 0, tvn = 0, rsn = 0;
        if (v + 16 < PER) {
            cn  = child_count[vg + 16];
            tvn = node_type[vg + 16];
            rsn = row_start[vg + 16];
        }

        float h4[4];
        if (c == 0) {
            ushort4b hv = *(const ushort4b*)&embh[(size_t)tv * XH + 4 * lane];
            #pragma unroll
            for (int i = 0; i < 4; i++) h4[i] = bf2f(hv[i]);
        } else {
            ushort4b yt = *(const ushort4b*)&Yt[(size_t)tv * XH + 4 * lane];  // bias folded
            float s4[4] = {0.f, 0.f, 0.f, 0.f};
            int e = rs, e1 = rs + c;
            for (; e + 2 <= e1; e += 2) {
                int2 p0 = epk[e], p1 = epk[e + 1];
                ushort8b w0 = *(const ushort8b*)&Ylr[(size_t)p0.x + 8 * lane];
                ushort8b w1 = *(const ushort8b*)&Ylr[(size_t)p1.x + 8 * lane];
                float a0 = __int_as_float(p0.y), a1 = __int_as_float(p1.y);
                #pragma unroll
                for (int i = 0; i < 4; i++) {
                    float l0 = bf2f(w0[2 * i]), r0 = bf2f(w0[2 * i + 1]);
                    s4[i] += l0 + a0 * (r0 - l0);
                }
                #pragma unroll
                for (int i = 0; i < 4; i++) {
                    float l1 = bf2f(w1[2 * i]), r1 = bf2f(w1[2 * i + 1]);
                    s4[i] += l1 + a1 * (r1 - l1);
                }
            }
            if (e < e1) {
                int2 p0 = epk[e];
                ushort8b w0 = *(const ushort8b*)&Ylr[(size_t)p0.x + 8 * lane];
                float a0 = __int_as_float(p0.y);
                #pragma unroll
                for (int i = 0; i < 4; i++) {
                    float l0 = bf2f(w0[2 * i]), r0 = bf2f(w0[2 * i + 1]);
                    s4[i] += l0 + a0 * (r0 - l0);
                }
            }
            #pragma unroll
            for (int i = 0; i < 4; i++)
                h4[i] = fmaxf(s4[i] + bf2f(yt[i]), 0.f);
        }

        float sg = h4[0] * gw4[0] + h4[1] * gw4[1] + h4[2] * gw4[2] + h4[3] * gw4[3];
        #pragma unroll
        for (int o = 1; o < 64; o <<= 1) sg += __shfl_xor(sg, o);
        float ew = __expf(sg + gb);
        dsum += ew;
        #pragma unroll
        for (int i = 0; i < 4; i++) acc4[i] += ew * h4[i];

        c = cn; tv = tvn; rs = rsn; vg += 16;
    }

    #pragma unroll
    for (int i = 0; i < 4; i++) pw[wv * XH + 4 * lane + i] = acc4[i];
    if (lane == 0) ds[wv] = dsum;
    __syncthreads();

    if (tid < XH) {
        float p = 0.f, d = 0.f;
        #pragma unroll
        for (int w = 0; w < 16; w++) p += pw[w * XH + tid];
        #pragma unroll
        for (int w = 0; w < 16; w++) d += ds[w];
        pooled[tid] = p / d;
    }
    __syncthreads();

    if (tid < NCLS) {
        float o = cls_b[tid];
        #pragma unroll 8
        for (int k = 0; k < XH; k++) o += pooled[k] * cls_w[k * NCLS + tid];
        out[g * NCLS + tid] = o;
    }
}

// ---------------------------------------------------------------------------
extern "C" void kernel_launch(void* const* d_in, const int* in_sizes, int n_in,
                              void* d_out, int out_size, void* d_ws, size_t ws_size,
                              hipStream_t stream) {
    const int*   node_type   = (const int*)d_in[0];
    const int*   edge_src    = (const int*)d_in[1];
    const int*   edge_dst    = (const int*)d_in[2];
    const float* alpha       = (const float*)d_in[3];
    const int*   child_count = (const int*)d_in[4];
    // d_in[5] graph_ids unused: nodes of a graph are contiguous
    const float* emb         = (const float*)d_in[6];
    const float* Wl          = (const float*)d_in[7];
    const float* Wr          = (const float*)d_in[8];
    const float* Wt          = (const float*)d_in[9];
    const float* b_conv      = (const float*)d_in[10];
    const float* gate_w      = (const float*)d_in[11];
    const float* gate_b      = (const float*)d_in[12];
    const float* cls_w       = (const float*)d_in[13];
    const float* cls_b       = (const float*)d_in[14];

    const int N     = in_sizes[0];
    const int E     = in_sizes[1];
    const int vocab = in_sizes[6] / XH;
    const int G     = out_size / NCLS;
    const int PER   = N / G;

    unsigned short* Ylr  = (unsigned short*)d_ws;               // vocab*512 bf16
    unsigned short* Yt   = Ylr + (size_t)vocab * 512;           // vocab*256 bf16
    unsigned short* embh = Yt + (size_t)vocab * XH;             // vocab*256 bf16
    unsigned short* Btw  = embh + (size_t)vocab * XH;           // 768*256 bf16
    int2*           epk  = (int2*)(Btw + 3 * XH * XH);          // E * 8B
    int*            row_start = (int*)(epk + E);                // N * 4B

    const int nprep = vocab * (XH / 4) + 3 * XH * XH + E;
    hipLaunchKernelGGL(k_prep, dim3((nprep + 255) / 256), dim3(256), 0, stream,
                       emb, Wl, Wr, Wt, edge_src, edge_dst, alpha, node_type,
                       embh, Btw, epk, row_start, vocab, E);

    hipLaunchKernelGGL(k_gemm, dim3(vocab / 128, 6), dim3(256), 0, stream,
                       embh, Btw, b_conv, Ylr, Yt);

    hipLaunchKernelGGL(k_graph, dim3(G), dim3(1024), 0, stream,
                       node_type, child_count, embh, Ylr, Yt, epk, row_start,
                       gate_w, gate_b, cls_w, cls_b, (float*)d_out, PER);
}